// Round 5
// baseline (5237.977 us; speedup 1.0000x reference)
//
#include <hip/hip_runtime.h>

// LSTMClassifier: B=4096, T=128, I=32, H=64, 2-layer LSTM + MLP head.
// Round 8: layer-split blocks. R7 proved the kernel is latency-bound per
// step (VALU diet: zero effect); the shared 8-wave barrier phase-locks the
// 2 waves/SIMD so they stall on the same chain. Split: L0 in blocks 0-255,
// L1 in blocks 256-511 (256 thr / 4 waves each; grid 512 = 2 blocks/CU,
// exactly resident; pair (i, i+256) lands on the same XCD since 256%8==0).
// Each block barriers only its own 4 waves; h0 crosses blocks via a global
// ring in d_ws with per-step flags:
//   producer wave: [ring stores] ... next step: __threadfence() (drains own
//     stores, ~1 step old) + relaxed flag+=1 (lane 0). Consumer waits ==4.
//   consumer: relaxed flag peek at step top (latency hidden under the whole
//     step), confirm+threadfence+prefetch frag loads at step end; MFMA uses
//     them NEXT step. Lag is elastic; ring depth D slots (pow2).
//   ring-reuse guard (only if D < TT): L1 publishes progress (relaxed);
//     L0 polls before overwriting a slot.
// Independent barriers => the L0 and L1 wave on a SIMD drift to anti-phase
// and fill each other's latency gaps. Eltwise: R7's validated 24-trans cell.
// Fallback: if ws_size too small for ring+flags, launch the proven R7 mono
// kernel (120us) unchanged.

#define TT 128
#define II 32

typedef _Float16 half8 __attribute__((ext_vector_type(8)));
typedef float floatx4 __attribute__((ext_vector_type(4)));

#define LOG2E 1.4426950408889634f

__device__ __forceinline__ half8 cvt_frag(float4 a, float4 b) {
    half8 h;
    h[0] = (_Float16)a.x; h[1] = (_Float16)a.y; h[2] = (_Float16)a.z; h[3] = (_Float16)a.w;
    h[4] = (_Float16)b.x; h[5] = (_Float16)b.y; h[6] = (_Float16)b.z; h[7] = (_Float16)b.w;
    return h;
}

// Load 8 consecutive fp32 of row n (K-major) as an f16 MFMA B-fragment.
__device__ __forceinline__ half8 load_w_frag(const float* __restrict__ W, int n, int K, int k0) {
    const float* p = W + (size_t)n * K + k0;
    return cvt_frag(*(const float4*)p, *(const float4*)(p + 4));
}

// LSTM cell eltwise, biases pre-folded (validated R6/R7: absmax 2.44e-4):
//   c = (c_prev*ds + (u-1)*df) * rcp(df*ds); h = (uc-1)*rcp((1+vo)(uc+1));
//   reciprocals paired across r. 24 trans/wave-step.
__device__ __forceinline__ void lstm_cell4(const floatx4* a, float* cr, float* hnew,
                                           float nbi, float nbf, float bg2, float nbo) {
    const float nL  = -LOG2E;
    const float p2L = 2.0f * LOG2E;
    const float C43 = 30.0f * LOG2E;
    float m[4], numc[4];
    #pragma unroll
    for (int r = 0; r < 4; ++r) {
        float vf = __builtin_amdgcn_exp2f(fmaf(a[1][r], nL, nbf));
        float tg = __builtin_amdgcn_fmed3f(fmaf(a[2][r], p2L, bg2), -C43, C43);
        float u  = __builtin_amdgcn_exp2f(tg);
        float vi = __builtin_amdgcn_exp2f(fmaf(a[0][r], nL, nbi));
        float du = u + 1.0f;
        float ds = fmaf(vi, du, du);
        float df = 1.0f + vf;
        m[r]    = df * ds;
        numc[r] = fmaf(cr[r], ds, (u - 1.0f) * df);
    }
    float r01 = __builtin_amdgcn_rcpf(m[0] * m[1]);
    float r23 = __builtin_amdgcn_rcpf(m[2] * m[3]);
    float c[4];
    c[0] = numc[0] * (r01 * m[1]);
    c[1] = numc[1] * (r01 * m[0]);
    c[2] = numc[2] * (r23 * m[3]);
    c[3] = numc[3] * (r23 * m[2]);
    float dh[4], un[4];
    #pragma unroll
    for (int r = 0; r < 4; ++r) {
        cr[r] = c[r];
        float vo = __builtin_amdgcn_exp2f(fmaf(a[3][r], nL, nbo));
        float tc = __builtin_amdgcn_fmed3f(c[r] * p2L, -C43, C43);
        float uc = __builtin_amdgcn_exp2f(tc);
        float du2 = uc + 1.0f;
        dh[r] = fmaf(vo, du2, du2);
        un[r] = uc - 1.0f;
    }
    float s01 = __builtin_amdgcn_rcpf(dh[0] * dh[1]);
    float s23 = __builtin_amdgcn_rcpf(dh[2] * dh[3]);
    hnew[0] = un[0] * (s01 * dh[1]);
    hnew[1] = un[1] * (s01 * dh[0]);
    hnew[2] = un[2] * (s23 * dh[3]);
    hnew[3] = un[3] * (s23 * dh[2]);
}

// ---------------- layer-split kernel: 512 blocks x 256 threads ----------------
__global__ __launch_bounds__(256, 2) void lstm_split(
    const float* __restrict__ x,
    const float* __restrict__ Wih0, const float* __restrict__ Whh0,
    const float* __restrict__ bih0, const float* __restrict__ bhh0,
    const float* __restrict__ Wih1, const float* __restrict__ Whh1,
    const float* __restrict__ bih1, const float* __restrict__ bhh1,
    const float* __restrict__ Wc1, const float* __restrict__ bc1,
    const float* __restrict__ Wc2, const float* __restrict__ bc2,
    float* __restrict__ out,
    unsigned* __restrict__ flags,   // [256][TT], memset 0 each launch
    int* __restrict__ prog,         // [256], memset 0 each launch
    _Float16* __restrict__ ring,    // [256][D][16][64]
    int D, int guard)
{
    __shared__ __align__(16) _Float16 xs[2][16][40];     // L0 only
    __shared__ __align__(16) _Float16 h0s[2][16][72];    // L0 only
    __shared__ __align__(16) _Float16 h1s[2][16][72];    // L1 only
    __shared__ __align__(16) float h1f[16][68];          // L1 only
    __shared__ float hid[16][32];                        // L1 only

    const int tid  = threadIdx.x;
    const int wid  = tid >> 6;        // wave 0..3
    const int w4   = wid;             // 16-channel group
    const int lane = tid & 63;
    const int q  = lane >> 4;
    const int lr = lane & 15;
    const bool isL0 = (blockIdx.x < 256);
    const int ib = isL0 ? blockIdx.x : blockIdx.x - 256;
    const int b0 = ib * 16;

    const float nL  = -LOG2E;
    const float p2L = 2.0f * LOG2E;
    const floatx4 zeroq = {0.f, 0.f, 0.f, 0.f};

    unsigned* myflags = flags + ib * TT;
    _Float16* myring  = ring + (size_t)ib * D * 1024;    // slot = 16x64 f16

    if (isL0) {
        // ---------------- layer-0 producer block ----------------
        half8 bx0[4], bh0[4][2];
        float bias[4];
        #pragma unroll
        for (int g = 0; g < 4; ++g) {
            int n = (w4 + 4 * g) * 16 + lr;
            bx0[g]    = load_w_frag(Wih0, n, 32, q * 8);
            bh0[g][0] = load_w_frag(Whh0, n, 64, q * 8);
            bh0[g][1] = load_w_frag(Whh0, n, 64, 32 + q * 8);
            bias[g]   = bih0[n] + bhh0[n];
        }
        const float nbi = nL * bias[0], nbf = nL * bias[1];
        const float bg2 = p2L * bias[2], nbo = nL * bias[3];

        for (int i2 = tid; i2 < 2 * 16 * 72; i2 += 256)
            ((_Float16*)h0s)[i2] = (_Float16)0.0f;       // h0(-1) = 0

        const int xm = tid >> 4;                 // 0..15
        const int xf = (tid & 15) * 2;
        const float* xrow = x + ((size_t)(b0 + xm) * TT) * II + xf;
        float2 x0 = *(const float2*)(xrow);              // x(0) -> xs[0]
        xs[0][xm][xf]     = (_Float16)x0.x;
        xs[0][xm][xf + 1] = (_Float16)x0.y;
        float2 xbuf = *(const float2*)(xrow + II);       // x(1) in regs

        float cr[4] = {0.f, 0.f, 0.f, 0.f};
        for (int t = 0; t < TT; ++t) {
            __syncthreads();                     // 4-wave private barrier
            if (t > 0) {
                // publish h0(t-1): fence drains THIS wave's ring stores
                // (issued a full step ago -> near-free), then flag += 1.
                __threadfence();
                if (lane == 0)
                    __hip_atomic_fetch_add(&myflags[t - 1], 1u,
                        __ATOMIC_RELAXED, __HIP_MEMORY_SCOPE_AGENT);
            }
            if (guard && t >= D) {               // ring-reuse guard (D < TT only)
                while (__hip_atomic_load(&prog[ib], __ATOMIC_RELAXED,
                        __HIP_MEMORY_SCOPE_AGENT) <= t - D)
                    __builtin_amdgcn_s_sleep(2);
            }
            const int rd = (t + 1) & 1, wr = t & 1;
            half8 xfrag = *(const half8*)&xs[wr][lr][q * 8];
            half8 h0a   = *(const half8*)&h0s[rd][lr][q * 8];
            half8 h0b   = *(const half8*)&h0s[rd][lr][32 + q * 8];
            float2 xnew = xbuf;
            if (t + 2 < TT) xnew = *(const float2*)(xrow + (size_t)(t + 2) * II);
            floatx4 a[4];
            #pragma unroll
            for (int g = 0; g < 4; ++g) {
                floatx4 acc = __builtin_amdgcn_mfma_f32_16x16x32_f16(xfrag, bx0[g],    zeroq, 0, 0, 0);
                acc         = __builtin_amdgcn_mfma_f32_16x16x32_f16(h0a,   bh0[g][0], acc,   0, 0, 0);
                a[g]        = __builtin_amdgcn_mfma_f32_16x16x32_f16(h0b,   bh0[g][1], acc,   0, 0, 0);
            }
            float hnew[4];
            lstm_cell4(a, cr, hnew, nbi, nbf, bg2, nbo);
            _Float16* sl = myring + (size_t)(t & (D - 1)) * 1024;
            #pragma unroll
            for (int r = 0; r < 4; ++r) {
                _Float16 hv = (_Float16)hnew[r];
                h0s[wr][q * 4 + r][w4 * 16 + lr] = hv;           // own next step
                sl[(q * 4 + r) * 64 + w4 * 16 + lr] = hv;        // ring for L1
            }
            if (t + 1 < TT) {
                xs[rd][xm][xf]     = (_Float16)xbuf.x;
                xs[rd][xm][xf + 1] = (_Float16)xbuf.y;
            }
            xbuf = xnew;
        }
        __threadfence();
        if (lane == 0)
            __hip_atomic_fetch_add(&myflags[TT - 1], 1u,
                __ATOMIC_RELAXED, __HIP_MEMORY_SCOPE_AGENT);
    } else {
        // ---------------- layer-1 consumer block ----------------
        half8 bi1[4][2], bh1[4][2];
        float bias[4];
        #pragma unroll
        for (int g = 0; g < 4; ++g) {
            int n = (w4 + 4 * g) * 16 + lr;
            bi1[g][0] = load_w_frag(Wih1, n, 64, q * 8);
            bi1[g][1] = load_w_frag(Wih1, n, 64, 32 + q * 8);
            bh1[g][0] = load_w_frag(Whh1, n, 64, q * 8);
            bh1[g][1] = load_w_frag(Whh1, n, 64, 32 + q * 8);
            bias[g]   = bih1[n] + bhh1[n];
        }
        const float nbi = nL * bias[0], nbf = nL * bias[1];
        const float bg2 = p2L * bias[2], nbo = nL * bias[3];

        for (int i2 = tid; i2 < 2 * 16 * 72; i2 += 256)
            ((_Float16*)h1s)[i2] = (_Float16)0.0f;       // h1(-1) = 0

        // prologue: wait for h0(0), prefetch its A-frags (coalesced dwordx4,
        // already in MFMA A-layout: lane lr = row, ch q*8..q*8+8).
        while (__hip_atomic_load(&myflags[0], __ATOMIC_RELAXED,
                __HIP_MEMORY_SCOPE_AGENT) < 4u)
            __builtin_amdgcn_s_sleep(2);
        __threadfence();
        const _Float16* s0 = myring + (size_t)lr * 64 + q * 8;
        half8 f0a = *(const half8*)s0;
        half8 f0b = *(const half8*)(s0 + 32);

        float cr[4] = {0.f, 0.f, 0.f, 0.f};
        for (int t = 0; t < TT; ++t) {
            __syncthreads();                     // 4-wave private barrier
            // early relaxed peek of next flag: value consumed ~a full step
            // later, so its latency hides under this step's compute.
            unsigned fv = 4u;
            if (t + 1 < TT)
                fv = __hip_atomic_load(&myflags[t + 1], __ATOMIC_RELAXED,
                        __HIP_MEMORY_SCOPE_AGENT);
            const int rd = (t + 1) & 1, wr = t & 1;
            half8 h1a = *(const half8*)&h1s[rd][lr][q * 8];
            half8 h1b = *(const half8*)&h1s[rd][lr][32 + q * 8];
            floatx4 a[4];
            #pragma unroll
            for (int g = 0; g < 4; ++g) {
                floatx4 acc = __builtin_amdgcn_mfma_f32_16x16x32_f16(f0a, bi1[g][0], zeroq, 0, 0, 0);
                acc         = __builtin_amdgcn_mfma_f32_16x16x32_f16(f0b, bi1[g][1], acc,   0, 0, 0);
                acc         = __builtin_amdgcn_mfma_f32_16x16x32_f16(h1a, bh1[g][0], acc,   0, 0, 0);
                a[g]        = __builtin_amdgcn_mfma_f32_16x16x32_f16(h1b, bh1[g][1], acc,   0, 0, 0);
            }
            // slots <= t fully consumed (MFMA waited on their loads)
            if (tid == 0)
                __hip_atomic_store(&prog[ib], t + 1,
                    __ATOMIC_RELAXED, __HIP_MEMORY_SCOPE_AGENT);
            float hnew[4];
            lstm_cell4(a, cr, hnew, nbi, nbf, bg2, nbo);
            if (t == TT - 1) {
                #pragma unroll
                for (int r = 0; r < 4; ++r)
                    h1f[q * 4 + r][w4 * 16 + lr] = hnew[r];
            } else {
                #pragma unroll
                for (int r = 0; r < 4; ++r)
                    h1s[wr][q * 4 + r][w4 * 16 + lr] = (_Float16)hnew[r];
            }
            if (t + 1 < TT) {                    // prefetch h0(t+1) frags
                if (fv < 4u) {
                    while (__hip_atomic_load(&myflags[t + 1], __ATOMIC_RELAXED,
                            __HIP_MEMORY_SCOPE_AGENT) < 4u)
                        __builtin_amdgcn_s_sleep(2);
                }
                __threadfence();                 // order frag loads after flag
                const _Float16* sl = myring
                    + (size_t)((t + 1) & (D - 1)) * 1024 + (size_t)lr * 64 + q * 8;
                f0a = *(const half8*)sl;
                f0b = *(const half8*)(sl + 32);
            }
        }
        __syncthreads();

        // ---- classifier (fp32), 256 threads ----
        {
            int m = tid >> 4;
            int u = (tid & 15) * 2;
            float aa = bc1[u], bb = bc1[u + 1];
            const float* w0 = Wc1 + u * 64;
            const float* w1 = Wc1 + (u + 1) * 64;
            #pragma unroll 8
            for (int kk = 0; kk < 64; ++kk) {
                float hv = h1f[m][kk];
                aa += hv * w0[kk];
                bb += hv * w1[kk];
            }
            hid[m][u]     = fmaxf(aa, 0.f);
            hid[m][u + 1] = fmaxf(bb, 0.f);
        }
        __syncthreads();
        if (tid < 16) {
            float o = bc2[0];
            #pragma unroll
            for (int u = 0; u < 32; ++u) o += hid[tid][u] * Wc2[u];
            out[b0 + tid] = o;
        }
    }
}

// ---------------- fallback: R7 mono kernel (proven 120us) ----------------
__global__ __launch_bounds__(512, 2) void lstm_fused_mono(
    const float* __restrict__ x,
    const float* __restrict__ Wih0, const float* __restrict__ Whh0,
    const float* __restrict__ bih0, const float* __restrict__ bhh0,
    const float* __restrict__ Wih1, const float* __restrict__ Whh1,
    const float* __restrict__ bih1, const float* __restrict__ bhh1,
    const float* __restrict__ Wc1, const float* __restrict__ bc1,
    const float* __restrict__ Wc2, const float* __restrict__ bc2,
    float* __restrict__ out)
{
    __shared__ __align__(16) _Float16 xs[2][16][40];
    __shared__ __align__(16) _Float16 h0s[2][16][72];
    __shared__ __align__(16) _Float16 h1s[2][16][72];
    __shared__ __align__(16) float h1f[16][68];
    __shared__ float hid[16][32];

    const int tid  = threadIdx.x;
    const int wid  = tid >> 6;
    const int w4   = wid & 3;
    const bool isL0 = (wid < 4);
    const int lane = tid & 63;
    const int q  = lane >> 4;
    const int lr = lane & 15;
    const int b0 = blockIdx.x * 16;

    const float nL  = -LOG2E;
    const float p2L = 2.0f * LOG2E;

    half8 bx0[4], bh0[4][2];
    half8 bi1[4][2], bh1[4][2];
    float bias[4];
    if (isL0) {
        #pragma unroll
        for (int g = 0; g < 4; ++g) {
            int n = (w4 + 4 * g) * 16 + lr;
            bx0[g]    = load_w_frag(Wih0, n, 32, q * 8);
            bh0[g][0] = load_w_frag(Whh0, n, 64, q * 8);
            bh0[g][1] = load_w_frag(Whh0, n, 64, 32 + q * 8);
            bias[g]   = bih0[n] + bhh0[n];
        }
    } else {
        #pragma unroll
        for (int g = 0; g < 4; ++g) {
            int n = (w4 + 4 * g) * 16 + lr;
            bi1[g][0] = load_w_frag(Wih1, n, 64, q * 8);
            bi1[g][1] = load_w_frag(Wih1, n, 64, 32 + q * 8);
            bh1[g][0] = load_w_frag(Whh1, n, 64, q * 8);
            bh1[g][1] = load_w_frag(Whh1, n, 64, 32 + q * 8);
            bias[g]   = bih1[n] + bhh1[n];
        }
    }
    const float nbi = nL * bias[0], nbf = nL * bias[1];
    const float bg2 = p2L * bias[2], nbo = nL * bias[3];
    const floatx4 zeroq = {0.f, 0.f, 0.f, 0.f};

    for (int i = tid; i < 2 * 16 * 72; i += 512) {
        ((_Float16*)h0s)[i] = (_Float16)0.0f;
        ((_Float16*)h1s)[i] = (_Float16)0.0f;
    }

    const int xm = (tid >> 4) & 15;
    const int xf = (tid & 15) * 2;
    const float* xrow = x + ((size_t)(b0 + xm) * TT) * II + xf;
    float2 xbuf = {0.f, 0.f};
    if (isL0) {
        float2 x0 = *(const float2*)(xrow);
        xs[0][xm][xf]     = (_Float16)x0.x;
        xs[0][xm][xf + 1] = (_Float16)x0.y;
        xbuf = *(const float2*)(xrow + II);
    }

    float cr[4] = {0.f, 0.f, 0.f, 0.f};

    for (int k = 0; k <= TT; ++k) {
        __syncthreads();
        const int rd = (k + 1) & 1;
        const int wr = k & 1;
        const bool doL0 = isL0 && (k < TT);
        const bool doL1 = (!isL0) && (k >= 1);
        floatx4 a[4];
        float hnew[4];
        float2 xnew = xbuf;

        if (doL0) {
            half8 xfrag = *(const half8*)&xs[wr][lr][q * 8];
            half8 h0a   = *(const half8*)&h0s[rd][lr][q * 8];
            half8 h0b   = *(const half8*)&h0s[rd][lr][32 + q * 8];
            if (k + 2 < TT) xnew = *(const float2*)(xrow + (size_t)(k + 2) * II);
            #pragma unroll
            for (int g = 0; g < 4; ++g) {
                floatx4 acc = __builtin_amdgcn_mfma_f32_16x16x32_f16(xfrag, bx0[g],    zeroq, 0, 0, 0);
                acc         = __builtin_amdgcn_mfma_f32_16x16x32_f16(h0a,   bh0[g][0], acc,   0, 0, 0);
                a[g]        = __builtin_amdgcn_mfma_f32_16x16x32_f16(h0b,   bh0[g][1], acc,   0, 0, 0);
            }
            lstm_cell4(a, cr, hnew, nbi, nbf, bg2, nbo);
        }
        if (doL1) {
            half8 g0a = *(const half8*)&h0s[rd][lr][q * 8];
            half8 g0b = *(const half8*)&h0s[rd][lr][32 + q * 8];
            half8 h1a = *(const half8*)&h1s[rd][lr][q * 8];
            half8 h1b = *(const half8*)&h1s[rd][lr][32 + q * 8];
            #pragma unroll
            for (int g = 0; g < 4; ++g) {
                floatx4 acc = __builtin_amdgcn_mfma_f32_16x16x32_f16(g0a, bi1[g][0], zeroq, 0, 0, 0);
                acc         = __builtin_amdgcn_mfma_f32_16x16x32_f16(g0b, bi1[g][1], acc,   0, 0, 0);
                acc         = __builtin_amdgcn_mfma_f32_16x16x32_f16(h1a, bh1[g][0], acc,   0, 0, 0);
                a[g]        = __builtin_amdgcn_mfma_f32_16x16x32_f16(h1b, bh1[g][1], acc,   0, 0, 0);
            }
            lstm_cell4(a, cr, hnew, nbi, nbf, bg2, nbo);
        }

        if (doL0) {
            #pragma unroll
            for (int r = 0; r < 4; ++r)
                h0s[wr][q * 4 + r][w4 * 16 + lr] = (_Float16)hnew[r];
            if (k + 1 < TT) {
                xs[rd][xm][xf]     = (_Float16)xbuf.x;
                xs[rd][xm][xf + 1] = (_Float16)xbuf.y;
            }
            xbuf = xnew;
        }
        if (doL1) {
            if (k == TT) {
                #pragma unroll
                for (int r = 0; r < 4; ++r)
                    h1f[q * 4 + r][w4 * 16 + lr] = hnew[r];
            } else {
                #pragma unroll
                for (int r = 0; r < 4; ++r)
                    h1s[wr][q * 4 + r][w4 * 16 + lr] = (_Float16)hnew[r];
            }
        }
    }
    __syncthreads();

    if (tid < 256) {
        int m = tid >> 4;
        int u = (tid & 15) * 2;
        float aa = bc1[u], bb = bc1[u + 1];
        const float* w0 = Wc1 + u * 64;
        const float* w1 = Wc1 + (u + 1) * 64;
        #pragma unroll 8
        for (int kk = 0; kk < 64; ++kk) {
            float hv = h1f[m][kk];
            aa += hv * w0[kk];
            bb += hv * w1[kk];
        }
        hid[m][u]     = fmaxf(aa, 0.f);
        hid[m][u + 1] = fmaxf(bb, 0.f);
    }
    __syncthreads();
    if (tid < 16) {
        float o = bc2[0];
        #pragma unroll
        for (int u = 0; u < 32; ++u) o += hid[tid][u] * Wc2[u];
        out[b0 + tid] = o;
    }
}

extern "C" void kernel_launch(void* const* d_in, const int* in_sizes, int n_in,
                              void* d_out, int out_size, void* d_ws, size_t ws_size,
                              hipStream_t stream) {
    (void)in_sizes; (void)n_in; (void)out_size;
    const float* x    = (const float*)d_in[0];
    const float* Wih0 = (const float*)d_in[1];
    const float* Whh0 = (const float*)d_in[2];
    const float* bih0 = (const float*)d_in[3];
    const float* bhh0 = (const float*)d_in[4];
    const float* Wih1 = (const float*)d_in[5];
    const float* Whh1 = (const float*)d_in[6];
    const float* bih1 = (const float*)d_in[7];
    const float* bhh1 = (const float*)d_in[8];
    const float* Wc1  = (const float*)d_in[9];
    const float* bc1  = (const float*)d_in[10];
    const float* Wc2  = (const float*)d_in[11];
    const float* bc2  = (const float*)d_in[12];

    // workspace layout: [flags 256*TT u32][prog 256 i32][ring 256*D*16*64 f16]
    const size_t FLAGB = (size_t)256 * TT * 4 + 1024;    // 132096 B (16-aligned)
    int D = 0;
    if (d_ws && ws_size >= FLAGB + (size_t)4 * 256 * 2048) {
        size_t slots = (ws_size - FLAGB) / ((size_t)256 * 2048);
        D = 4;
        while (D < TT && (size_t)(D * 2) <= slots) D *= 2;
    }
    if (D > 0) {
        hipMemsetAsync(d_ws, 0, FLAGB, stream);
        unsigned* flags = (unsigned*)d_ws;
        int* prog = (int*)((char*)d_ws + (size_t)256 * TT * 4);
        _Float16* ring = (_Float16*)((char*)d_ws + FLAGB);
        lstm_split<<<dim3(512), dim3(256), 0, stream>>>(
            x, Wih0, Whh0, bih0, bhh0, Wih1, Whh1, bih1, bhh1, Wc1, bc1, Wc2, bc2,
            (float*)d_out, flags, prog, ring, D, (D < TT) ? 1 : 0);
    } else {
        lstm_fused_mono<<<dim3(256), dim3(512), 0, stream>>>(
            x, Wih0, Whh0, bih0, bhh0, Wih1, Whh1, bih1, bhh1, Wc1, bc1, Wc2, bc2,
            (float*)d_out);
    }
}

// Round 6
// 216.392 us; speedup vs baseline: 24.2060x; 24.2060x over previous
//
#include <hip/hip_runtime.h>

// LSTMClassifier: B=4096, T=128, I=32, H=64, 2-layer LSTM + MLP head.
// Round 9: both layers in ONE wave (ILP not TLP).
//   History: R3/R7 single-barrier 8-wave = 120us. R5 (LDS counters), R6
//   (2-slot anti-phase), R8 (cross-block global ring: 5.5ms!) all proved
//   cross-WAVE de-phasing costs more sync than it recovers; R7 proved the
//   kernel is latency-bound, not issue-bound. Remaining lever: put L0(k)
//   and L1(k-1) in the SAME instruction stream so the compiler interleaves
//   L1's MFMA chain under L0's eltwise chain (and vice versa) -- the
//   anti-phase overlap with ZERO added sync.
//   256 thr/block, 4 waves; wave w owns channels [16w,16w+16) of BOTH
//   layers (weights for both persist in registers, ~112 VGPR). The
//   h0(k-1) A-fragment is shared by L0's Whh0 GEMM and L1's Wih1 GEMM:
//   one LDS read feeds both (h0 ds_read traffic halves). One barrier per
//   step over 4 symmetric waves; peeled prologue/epilogue make the main
//   loop branch-free. Buffer parities identical to proven R7.
// Eltwise: R6/R7-validated 24-trans fused cell (absmax 2.44e-4).
// f16 MFMA operands, fp32 accumulate/state. 256 blocks x 256 threads.

#define TT 128
#define II 32

typedef _Float16 half8 __attribute__((ext_vector_type(8)));
typedef float floatx4 __attribute__((ext_vector_type(4)));

#define LOG2E 1.4426950408889634f

__device__ __forceinline__ half8 cvt_frag(float4 a, float4 b) {
    half8 h;
    h[0] = (_Float16)a.x; h[1] = (_Float16)a.y; h[2] = (_Float16)a.z; h[3] = (_Float16)a.w;
    h[4] = (_Float16)b.x; h[5] = (_Float16)b.y; h[6] = (_Float16)b.z; h[7] = (_Float16)b.w;
    return h;
}

// Load 8 consecutive fp32 of row n (K-major) as an f16 MFMA B-fragment.
__device__ __forceinline__ half8 load_w_frag(const float* __restrict__ W, int n, int K, int k0) {
    const float* p = W + (size_t)n * K + k0;
    return cvt_frag(*(const float4*)p, *(const float4*)(p + 4));
}

// LSTM cell eltwise, biases pre-folded (validated R6/R7: absmax 2.44e-4):
//   c = (c_prev*ds + (u-1)*df) * rcp(df*ds); h = (uc-1)*rcp((1+vo)(uc+1));
//   reciprocals paired across r. 24 trans per call.
__device__ __forceinline__ void lstm_cell4(const floatx4* a, float* cr, float* hnew,
                                           float nbi, float nbf, float bg2, float nbo) {
    const float nL  = -LOG2E;
    const float p2L = 2.0f * LOG2E;
    const float C43 = 30.0f * LOG2E;
    float m[4], numc[4];
    #pragma unroll
    for (int r = 0; r < 4; ++r) {
        float vf = __builtin_amdgcn_exp2f(fmaf(a[1][r], nL, nbf));
        float tg = __builtin_amdgcn_fmed3f(fmaf(a[2][r], p2L, bg2), -C43, C43);
        float u  = __builtin_amdgcn_exp2f(tg);
        float vi = __builtin_amdgcn_exp2f(fmaf(a[0][r], nL, nbi));
        float du = u + 1.0f;
        float ds = fmaf(vi, du, du);
        float df = 1.0f + vf;
        m[r]    = df * ds;
        numc[r] = fmaf(cr[r], ds, (u - 1.0f) * df);
    }
    float r01 = __builtin_amdgcn_rcpf(m[0] * m[1]);
    float r23 = __builtin_amdgcn_rcpf(m[2] * m[3]);
    float c[4];
    c[0] = numc[0] * (r01 * m[1]);
    c[1] = numc[1] * (r01 * m[0]);
    c[2] = numc[2] * (r23 * m[3]);
    c[3] = numc[3] * (r23 * m[2]);
    float dh[4], un[4];
    #pragma unroll
    for (int r = 0; r < 4; ++r) {
        cr[r] = c[r];
        float vo = __builtin_amdgcn_exp2f(fmaf(a[3][r], nL, nbo));
        float tc = __builtin_amdgcn_fmed3f(c[r] * p2L, -C43, C43);
        float uc = __builtin_amdgcn_exp2f(tc);
        float du2 = uc + 1.0f;
        dh[r] = fmaf(vo, du2, du2);
        un[r] = uc - 1.0f;
    }
    float s01 = __builtin_amdgcn_rcpf(dh[0] * dh[1]);
    float s23 = __builtin_amdgcn_rcpf(dh[2] * dh[3]);
    hnew[0] = un[0] * (s01 * dh[1]);
    hnew[1] = un[1] * (s01 * dh[0]);
    hnew[2] = un[2] * (s23 * dh[3]);
    hnew[3] = un[3] * (s23 * dh[2]);
}

__global__ __launch_bounds__(256, 1) void lstm_fused(
    const float* __restrict__ x,
    const float* __restrict__ Wih0, const float* __restrict__ Whh0,
    const float* __restrict__ bih0, const float* __restrict__ bhh0,
    const float* __restrict__ Wih1, const float* __restrict__ Whh1,
    const float* __restrict__ bih1, const float* __restrict__ bhh1,
    const float* __restrict__ Wc1, const float* __restrict__ bc1,
    const float* __restrict__ Wc2, const float* __restrict__ bc2,
    float* __restrict__ out)
{
    // 72-f16 row stride (144B): b128 reads at free 2-way bank alias (m136).
    __shared__ __align__(16) _Float16 xs[2][16][40];
    __shared__ __align__(16) _Float16 h0s[2][16][72];
    __shared__ __align__(16) _Float16 h1s[2][16][72];
    __shared__ __align__(16) float h1f[16][68];   // final-step h1 (fp32)
    __shared__ float hid[16][32];

    const int tid  = threadIdx.x;
    const int w4   = tid >> 6;        // wave 0..3 = 16-channel group (both layers)
    const int lane = tid & 63;
    const int q  = lane >> 4;         // quad 0..3
    const int lr = lane & 15;
    const int b0 = blockIdx.x * 16;

    const float nL  = -LOG2E;
    const float p2L = 2.0f * LOG2E;

    // ---- persistent weight fragments for BOTH layers (registers) ----
    half8 bx0[4], bh0[4][2], bi1[4][2], bh1[4][2];
    float bias0[4], bias1[4];
    #pragma unroll
    for (int g = 0; g < 4; ++g) {
        int n = (w4 + 4 * g) * 16 + lr;
        bx0[g]    = load_w_frag(Wih0, n, 32, q * 8);
        bh0[g][0] = load_w_frag(Whh0, n, 64, q * 8);
        bh0[g][1] = load_w_frag(Whh0, n, 64, 32 + q * 8);
        bias0[g]  = bih0[n] + bhh0[n];
        bi1[g][0] = load_w_frag(Wih1, n, 64, q * 8);
        bi1[g][1] = load_w_frag(Wih1, n, 64, 32 + q * 8);
        bh1[g][0] = load_w_frag(Whh1, n, 64, q * 8);
        bh1[g][1] = load_w_frag(Whh1, n, 64, 32 + q * 8);
        bias1[g]  = bih1[n] + bhh1[n];
    }
    const float nbi0 = nL * bias0[0], nbf0 = nL * bias0[1];
    const float bg20 = p2L * bias0[2], nbo0 = nL * bias0[3];
    const float nbi1 = nL * bias1[0], nbf1 = nL * bias1[1];
    const float bg21 = p2L * bias1[2], nbo1 = nL * bias1[3];
    const floatx4 zeroq = {0.f, 0.f, 0.f, 0.f};

    // zero-init both h buffers (h0(-1) = h1(-1) = 0)
    for (int i = tid; i < 2 * 16 * 72; i += 256) {
        ((_Float16*)h0s)[i] = (_Float16)0.0f;
        ((_Float16*)h1s)[i] = (_Float16)0.0f;
    }

    // x staging: thread -> (row xm, 2 consecutive floats); 256 thr = 16x32
    const int xm = tid >> 4;
    const int xf = (tid & 15) * 2;
    const float* xrow = x + ((size_t)(b0 + xm) * TT) * II + xf;
    float2 x0v = *(const float2*)(xrow);               // x(0) -> xs[0]
    xs[0][xm][xf]     = (_Float16)x0v.x;
    xs[0][xm][xf + 1] = (_Float16)x0v.y;
    float2 xbuf = *(const float2*)(xrow + II);         // x(1) in regs

    float cr0[4] = {0.f, 0.f, 0.f, 0.f};
    float cr1[4] = {0.f, 0.f, 0.f, 0.f};
    float hnew[4];
    floatx4 a0[4], a1[4];

    __syncthreads();

    // ---- prologue (k=0): L0(0) only ----
    {
        half8 xfrag = *(const half8*)&xs[0][lr][q * 8];
        half8 h0a   = *(const half8*)&h0s[1][lr][q * 8];
        half8 h0b   = *(const half8*)&h0s[1][lr][32 + q * 8];
        float2 xnew = *(const float2*)(xrow + 2 * II); // x(2)
        #pragma unroll
        for (int g = 0; g < 4; ++g) {
            floatx4 acc = __builtin_amdgcn_mfma_f32_16x16x32_f16(xfrag, bx0[g],    zeroq, 0, 0, 0);
            acc         = __builtin_amdgcn_mfma_f32_16x16x32_f16(h0a,   bh0[g][0], acc,   0, 0, 0);
            a0[g]       = __builtin_amdgcn_mfma_f32_16x16x32_f16(h0b,   bh0[g][1], acc,   0, 0, 0);
        }
        lstm_cell4(a0, cr0, hnew, nbi0, nbf0, bg20, nbo0);
        #pragma unroll
        for (int r = 0; r < 4; ++r)
            h0s[0][q * 4 + r][w4 * 16 + lr] = (_Float16)hnew[r];
        xs[1][xm][xf]     = (_Float16)xbuf.x;          // stage x(1)
        xs[1][xm][xf + 1] = (_Float16)xbuf.y;
        xbuf = xnew;
    }

    // ---- main loop k=1..TT-1: L0(k) + L1(k-1) fused in one stream ----
    // Parities verbatim from R7: rd=(k+1)&1, wr=k&1.
    //   L0 reads h0s[rd] (h0(k-1)), xs[wr] (x(k)); writes h0s[wr] (h0(k)).
    //   L1 reads h0s[rd] (SAME frags), h1s[rd] (h1(k-2)); writes h1s[wr].
    for (int k = 1; k < TT; ++k) {
        __syncthreads();
        const int rd = (k + 1) & 1;
        const int wr = k & 1;

        half8 xfrag = *(const half8*)&xs[wr][lr][q * 8];
        half8 h0a   = *(const half8*)&h0s[rd][lr][q * 8];
        half8 h0b   = *(const half8*)&h0s[rd][lr][32 + q * 8];
        half8 h1a   = *(const half8*)&h1s[rd][lr][q * 8];
        half8 h1b   = *(const half8*)&h1s[rd][lr][32 + q * 8];
        float2 xnew = xbuf;
        if (k + 2 < TT) xnew = *(const float2*)(xrow + (size_t)(k + 2) * II);

        #pragma unroll
        for (int g = 0; g < 4; ++g) {
            floatx4 acc = __builtin_amdgcn_mfma_f32_16x16x32_f16(xfrag, bx0[g],    zeroq, 0, 0, 0);
            acc         = __builtin_amdgcn_mfma_f32_16x16x32_f16(h0a,   bh0[g][0], acc,   0, 0, 0);
            a0[g]       = __builtin_amdgcn_mfma_f32_16x16x32_f16(h0b,   bh0[g][1], acc,   0, 0, 0);
        }
        #pragma unroll
        for (int g = 0; g < 4; ++g) {
            floatx4 acc = __builtin_amdgcn_mfma_f32_16x16x32_f16(h0a, bi1[g][0], zeroq, 0, 0, 0);
            acc         = __builtin_amdgcn_mfma_f32_16x16x32_f16(h0b, bi1[g][1], acc,   0, 0, 0);
            acc         = __builtin_amdgcn_mfma_f32_16x16x32_f16(h1a, bh1[g][0], acc,   0, 0, 0);
            a1[g]       = __builtin_amdgcn_mfma_f32_16x16x32_f16(h1b, bh1[g][1], acc,   0, 0, 0);
        }

        lstm_cell4(a0, cr0, hnew, nbi0, nbf0, bg20, nbo0);
        #pragma unroll
        for (int r = 0; r < 4; ++r)
            h0s[wr][q * 4 + r][w4 * 16 + lr] = (_Float16)hnew[r];
        if (k + 1 < TT) {                              // stage x(k+1)
            xs[rd][xm][xf]     = (_Float16)xbuf.x;
            xs[rd][xm][xf + 1] = (_Float16)xbuf.y;
        }
        xbuf = xnew;

        lstm_cell4(a1, cr1, hnew, nbi1, nbf1, bg21, nbo1);
        #pragma unroll
        for (int r = 0; r < 4; ++r)
            h1s[wr][q * 4 + r][w4 * 16 + lr] = (_Float16)hnew[r];
    }

    // ---- epilogue (k=TT): L1(TT-1) only -> h1f (fp32) ----
    {
        __syncthreads();
        const int rd = (TT + 1) & 1;                   // = 1
        half8 h0a = *(const half8*)&h0s[rd][lr][q * 8];
        half8 h0b = *(const half8*)&h0s[rd][lr][32 + q * 8];
        half8 h1a = *(const half8*)&h1s[rd][lr][q * 8];
        half8 h1b = *(const half8*)&h1s[rd][lr][32 + q * 8];
        #pragma unroll
        for (int g = 0; g < 4; ++g) {
            floatx4 acc = __builtin_amdgcn_mfma_f32_16x16x32_f16(h0a, bi1[g][0], zeroq, 0, 0, 0);
            acc         = __builtin_amdgcn_mfma_f32_16x16x32_f16(h0b, bi1[g][1], acc,   0, 0, 0);
            acc         = __builtin_amdgcn_mfma_f32_16x16x32_f16(h1a, bh1[g][0], acc,   0, 0, 0);
            a1[g]       = __builtin_amdgcn_mfma_f32_16x16x32_f16(h1b, bh1[g][1], acc,   0, 0, 0);
        }
        lstm_cell4(a1, cr1, hnew, nbi1, nbf1, bg21, nbo1);
        #pragma unroll
        for (int r = 0; r < 4; ++r)
            h1f[q * 4 + r][w4 * 16 + lr] = hnew[r];
    }
    __syncthreads();

    // ---- classifier (fp32): hidden = relu(hT Wc1^T + bc1); out = hidden Wc2^T + bc2
    {
        int m = tid >> 4;
        int u = (tid & 15) * 2;
        float aa = bc1[u], bb = bc1[u + 1];
        const float* w0 = Wc1 + u * 64;
        const float* w1 = Wc1 + (u + 1) * 64;
        #pragma unroll 8
        for (int kk = 0; kk < 64; ++kk) {
            float hv = h1f[m][kk];
            aa += hv * w0[kk];
            bb += hv * w1[kk];
        }
        hid[m][u]     = fmaxf(aa, 0.f);
        hid[m][u + 1] = fmaxf(bb, 0.f);
    }
    __syncthreads();
    if (tid < 16) {
        float o = bc2[0];
        #pragma unroll
        for (int u = 0; u < 32; ++u) o += hid[tid][u] * Wc2[u];
        out[b0 + tid] = o;
    }
}

extern "C" void kernel_launch(void* const* d_in, const int* in_sizes, int n_in,
                              void* d_out, int out_size, void* d_ws, size_t ws_size,
                              hipStream_t stream) {
    (void)in_sizes; (void)n_in; (void)d_ws; (void)ws_size; (void)out_size;
    const float* x    = (const float*)d_in[0];
    const float* Wih0 = (const float*)d_in[1];
    const float* Whh0 = (const float*)d_in[2];
    const float* bih0 = (const float*)d_in[3];
    const float* bhh0 = (const float*)d_in[4];
    const float* Wih1 = (const float*)d_in[5];
    const float* Whh1 = (const float*)d_in[6];
    const float* bih1 = (const float*)d_in[7];
    const float* bhh1 = (const float*)d_in[8];
    const float* Wc1  = (const float*)d_in[9];
    const float* bc1  = (const float*)d_in[10];
    const float* Wc2  = (const float*)d_in[11];
    const float* bc2  = (const float*)d_in[12];
    lstm_fused<<<dim3(256), dim3(256), 0, stream>>>(
        x, Wih0, Whh0, bih0, bhh0, Wih1, Whh1, bih1, bhh1, Wc1, bc1, Wc2, bc2,
        (float*)d_out);
}

// Round 7
// 204.058 us; speedup vs baseline: 25.6690x; 1.0604x over previous
//
#include <hip/hip_runtime.h>

// LSTMClassifier: B=4096, T=128, I=32, H=64, 2-layer LSTM + MLP head.
// Round 10: surgical issue-diet on the proven R3/R7 topology (120us), after
// R4/R5/R6/R8/R9 all proved every alternative topology is worse:
//   - 8 waves, ONE barrier/step, LDS x-staging, dbuf f16 h-state (R7 exact).
//   - NEW: main loop unrolled x2 with COMPILE-TIME parities (k=0,127,128
//     peeled). All LDS addresses loop-invariant -> hoisted once; kills the
//     per-step parity/address VALU that dominated the unexplained issue.
//   - NEW: lgkm-only barrier (s_waitcnt lgkmcnt(0); s_barrier) instead of
//     __syncthreads' full vmcnt(0)+lgkmcnt(0) drain. All cross-wave deps
//     are LDS; private x-prefetch stays in flight across the barrier.
//   - Eltwise: R6/R7-validated 24-trans fused cell (absmax 2.44e-4).
// f16 MFMA operands, fp32 accumulate/state. 256 blocks x 512 threads.

#define TT 128
#define II 32

typedef _Float16 half8 __attribute__((ext_vector_type(8)));
typedef float floatx4 __attribute__((ext_vector_type(4)));

#define LOG2E 1.4426950408889634f

__device__ __forceinline__ half8 cvt_frag(float4 a, float4 b) {
    half8 h;
    h[0] = (_Float16)a.x; h[1] = (_Float16)a.y; h[2] = (_Float16)a.z; h[3] = (_Float16)a.w;
    h[4] = (_Float16)b.x; h[5] = (_Float16)b.y; h[6] = (_Float16)b.z; h[7] = (_Float16)b.w;
    return h;
}

// Load 8 consecutive fp32 of row n (K-major) as an f16 MFMA B-fragment.
__device__ __forceinline__ half8 load_w_frag(const float* __restrict__ W, int n, int K, int k0) {
    const float* p = W + (size_t)n * K + k0;
    return cvt_frag(*(const float4*)p, *(const float4*)(p + 4));
}

// Workgroup barrier draining LDS ops only (not vmcnt): cross-wave data all
// flows through LDS; each wave's private global x-prefetch may stay in
// flight (compiler inserts its vmcnt wait at the consuming instruction).
__device__ __forceinline__ void bar_lgkm() {
    asm volatile("s_waitcnt lgkmcnt(0)\n\ts_barrier" ::: "memory");
}

// LSTM cell eltwise, biases pre-folded (validated R6/R7: absmax 2.44e-4):
//   c = (c_prev*ds + (u-1)*df) * rcp(df*ds); h = (uc-1)*rcp((1+vo)(uc+1));
//   reciprocals paired across r. 24 trans per call.
__device__ __forceinline__ void lstm_cell4(const floatx4* a, float* cr, float* hnew,
                                           float nbi, float nbf, float bg2, float nbo) {
    const float nL  = -LOG2E;
    const float p2L = 2.0f * LOG2E;
    const float C43 = 30.0f * LOG2E;
    float m[4], numc[4];
    #pragma unroll
    for (int r = 0; r < 4; ++r) {
        float vf = __builtin_amdgcn_exp2f(fmaf(a[1][r], nL, nbf));
        float tg = __builtin_amdgcn_fmed3f(fmaf(a[2][r], p2L, bg2), -C43, C43);
        float u  = __builtin_amdgcn_exp2f(tg);
        float vi = __builtin_amdgcn_exp2f(fmaf(a[0][r], nL, nbi));
        float du = u + 1.0f;
        float ds = fmaf(vi, du, du);
        float df = 1.0f + vf;
        m[r]    = df * ds;
        numc[r] = fmaf(cr[r], ds, (u - 1.0f) * df);
    }
    float r01 = __builtin_amdgcn_rcpf(m[0] * m[1]);
    float r23 = __builtin_amdgcn_rcpf(m[2] * m[3]);
    float c[4];
    c[0] = numc[0] * (r01 * m[1]);
    c[1] = numc[1] * (r01 * m[0]);
    c[2] = numc[2] * (r23 * m[3]);
    c[3] = numc[3] * (r23 * m[2]);
    float dh[4], un[4];
    #pragma unroll
    for (int r = 0; r < 4; ++r) {
        cr[r] = c[r];
        float vo = __builtin_amdgcn_exp2f(fmaf(a[3][r], nL, nbo));
        float tc = __builtin_amdgcn_fmed3f(c[r] * p2L, -C43, C43);
        float uc = __builtin_amdgcn_exp2f(tc);
        float du2 = uc + 1.0f;
        dh[r] = fmaf(vo, du2, du2);
        un[r] = uc - 1.0f;
    }
    float s01 = __builtin_amdgcn_rcpf(dh[0] * dh[1]);
    float s23 = __builtin_amdgcn_rcpf(dh[2] * dh[3]);
    hnew[0] = un[0] * (s01 * dh[1]);
    hnew[1] = un[1] * (s01 * dh[0]);
    hnew[2] = un[2] * (s23 * dh[3]);
    hnew[3] = un[3] * (s23 * dh[2]);
}

// One R7 iteration with compile-time parities RD/WR. At iteration kk:
// L0 waves compute h0(kk) (reads xs[WR]=x(kk), h0s[RD]=h0(kk-1), writes
// h0s[WR]); L1 waves compute h1(kk-1) (reads h0s[RD], h1s[RD], writes
// h1s[WR]). Used only for 1 <= kk <= TT-1 (both groups active).
#define STEP(kk, RD, WR)                                                        \
    {                                                                           \
        bar_lgkm();                                                             \
        if (isL0) {                                                             \
            half8 xfrag = *(const half8*)&xs[WR][lr][q * 8];                    \
            half8 h0a   = *(const half8*)&h0s[RD][lr][q * 8];                   \
            half8 h0b   = *(const half8*)&h0s[RD][lr][32 + q * 8];              \
            float2 xnew = xbuf;                                                 \
            if ((kk) + 2 < TT) xnew = *(const float2*)(xrow + (size_t)((kk) + 2) * II); \
            floatx4 a[4];                                                       \
            _Pragma("unroll")                                                   \
            for (int g = 0; g < 4; ++g) {                                       \
                floatx4 acc = __builtin_amdgcn_mfma_f32_16x16x32_f16(xfrag, bx0[g],    zeroq, 0, 0, 0); \
                acc         = __builtin_amdgcn_mfma_f32_16x16x32_f16(h0a,   bh0[g][0], acc,   0, 0, 0); \
                a[g]        = __builtin_amdgcn_mfma_f32_16x16x32_f16(h0b,   bh0[g][1], acc,   0, 0, 0); \
            }                                                                   \
            float hnew[4];                                                      \
            lstm_cell4(a, cr, hnew, nbi, nbf, bg2, nbo);                        \
            _Pragma("unroll")                                                   \
            for (int r = 0; r < 4; ++r)                                         \
                h0s[WR][q * 4 + r][w4 * 16 + lr] = (_Float16)hnew[r];           \
            if ((kk) + 1 < TT) {                                                \
                xs[RD][xm][xf]     = (_Float16)xbuf.x;                          \
                xs[RD][xm][xf + 1] = (_Float16)xbuf.y;                          \
            }                                                                   \
            xbuf = xnew;                                                        \
        } else {                                                                \
            half8 g0a = *(const half8*)&h0s[RD][lr][q * 8];                     \
            half8 g0b = *(const half8*)&h0s[RD][lr][32 + q * 8];                \
            half8 h1a = *(const half8*)&h1s[RD][lr][q * 8];                     \
            half8 h1b = *(const half8*)&h1s[RD][lr][32 + q * 8];                \
            floatx4 a[4];                                                       \
            _Pragma("unroll")                                                   \
            for (int g = 0; g < 4; ++g) {                                       \
                floatx4 acc = __builtin_amdgcn_mfma_f32_16x16x32_f16(g0a, bi1[g][0], zeroq, 0, 0, 0); \
                acc         = __builtin_amdgcn_mfma_f32_16x16x32_f16(g0b, bi1[g][1], acc,   0, 0, 0); \
                acc         = __builtin_amdgcn_mfma_f32_16x16x32_f16(h1a, bh1[g][0], acc,   0, 0, 0); \
                a[g]        = __builtin_amdgcn_mfma_f32_16x16x32_f16(h1b, bh1[g][1], acc,   0, 0, 0); \
            }                                                                   \
            float hnew[4];                                                      \
            lstm_cell4(a, cr, hnew, nbi, nbf, bg2, nbo);                        \
            _Pragma("unroll")                                                   \
            for (int r = 0; r < 4; ++r)                                         \
                h1s[WR][q * 4 + r][w4 * 16 + lr] = (_Float16)hnew[r];           \
        }                                                                       \
    }

__global__ __launch_bounds__(512, 2) void lstm_fused(
    const float* __restrict__ x,
    const float* __restrict__ Wih0, const float* __restrict__ Whh0,
    const float* __restrict__ bih0, const float* __restrict__ bhh0,
    const float* __restrict__ Wih1, const float* __restrict__ Whh1,
    const float* __restrict__ bih1, const float* __restrict__ bhh1,
    const float* __restrict__ Wc1, const float* __restrict__ bc1,
    const float* __restrict__ Wc2, const float* __restrict__ bc2,
    float* __restrict__ out)
{
    // 72-f16 row stride (144B): b128 reads at free 2-way bank alias (m136).
    __shared__ __align__(16) _Float16 xs[2][16][40];
    __shared__ __align__(16) _Float16 h0s[2][16][72];
    __shared__ __align__(16) _Float16 h1s[2][16][72];
    __shared__ __align__(16) float h1f[16][68];   // final-step h1 (fp32)
    __shared__ float hid[16][32];

    const int tid  = threadIdx.x;
    const int wid  = tid >> 6;        // wave 0..7
    const int w4   = wid & 3;         // channel-group within the layer
    const bool isL0 = (wid < 4);
    const int lane = tid & 63;
    const int q  = lane >> 4;         // quad 0..3
    const int lr = lane & 15;
    const int b0 = blockIdx.x * 16;

    const float nL  = -LOG2E;
    const float p2L = 2.0f * LOG2E;

    // ---- persistent weight fragments (registers, whole kernel) ----
    half8 bx0[4], bh0[4][2];          // layer-0 waves
    half8 bi1[4][2], bh1[4][2];       // layer-1 waves
    float bias[4];
    if (isL0) {
        #pragma unroll
        for (int g = 0; g < 4; ++g) {
            int n = (w4 + 4 * g) * 16 + lr;
            bx0[g]    = load_w_frag(Wih0, n, 32, q * 8);
            bh0[g][0] = load_w_frag(Whh0, n, 64, q * 8);
            bh0[g][1] = load_w_frag(Whh0, n, 64, 32 + q * 8);
            bias[g]   = bih0[n] + bhh0[n];
        }
    } else {
        #pragma unroll
        for (int g = 0; g < 4; ++g) {
            int n = (w4 + 4 * g) * 16 + lr;
            bi1[g][0] = load_w_frag(Wih1, n, 64, q * 8);
            bi1[g][1] = load_w_frag(Wih1, n, 64, 32 + q * 8);
            bh1[g][0] = load_w_frag(Whh1, n, 64, q * 8);
            bh1[g][1] = load_w_frag(Whh1, n, 64, 32 + q * 8);
            bias[g]   = bih1[n] + bhh1[n];
        }
    }
    const float nbi = nL * bias[0], nbf = nL * bias[1];
    const float bg2 = p2L * bias[2], nbo = nL * bias[3];
    const floatx4 zeroq = {0.f, 0.f, 0.f, 0.f};

    // zero-init both h-state buffers (h0(-1) = h1(-1) = 0)
    for (int i = tid; i < 2 * 16 * 72; i += 512) {
        ((_Float16*)h0s)[i] = (_Float16)0.0f;
        ((_Float16*)h1s)[i] = (_Float16)0.0f;
    }

    // x staging (layer-0 waves only): thread -> (row xm, 2 consecutive floats)
    const int xm = (tid >> 4) & 15;
    const int xf = (tid & 15) * 2;
    const float* xrow = x + ((size_t)(b0 + xm) * TT) * II + xf;
    float2 xbuf = {0.f, 0.f};
    if (isL0) {
        float2 x0 = *(const float2*)(xrow);            // x(0) -> xs[0]
        xs[0][xm][xf]     = (_Float16)x0.x;
        xs[0][xm][xf + 1] = (_Float16)x0.y;
        xbuf = *(const float2*)(xrow + II);            // x(1) in regs
    }

    float cr[4] = {0.f, 0.f, 0.f, 0.f};   // c state for this wave's layer

    // ---- k=0 peel: L0 only (RD=1: h0(-1)=zeros; WR=0) ----
    bar_lgkm();
    if (isL0) {
        half8 xfrag = *(const half8*)&xs[0][lr][q * 8];
        half8 h0a   = *(const half8*)&h0s[1][lr][q * 8];
        half8 h0b   = *(const half8*)&h0s[1][lr][32 + q * 8];
        float2 xnew = *(const float2*)(xrow + 2 * II);   // x(2)
        floatx4 a[4];
        #pragma unroll
        for (int g = 0; g < 4; ++g) {
            floatx4 acc = __builtin_amdgcn_mfma_f32_16x16x32_f16(xfrag, bx0[g],    zeroq, 0, 0, 0);
            acc         = __builtin_amdgcn_mfma_f32_16x16x32_f16(h0a,   bh0[g][0], acc,   0, 0, 0);
            a[g]        = __builtin_amdgcn_mfma_f32_16x16x32_f16(h0b,   bh0[g][1], acc,   0, 0, 0);
        }
        float hnew[4];
        lstm_cell4(a, cr, hnew, nbi, nbf, bg2, nbo);
        #pragma unroll
        for (int r = 0; r < 4; ++r)
            h0s[0][q * 4 + r][w4 * 16 + lr] = (_Float16)hnew[r];
        xs[1][xm][xf]     = (_Float16)xbuf.x;            // stage x(1)
        xs[1][xm][xf + 1] = (_Float16)xbuf.y;
        xbuf = xnew;
    }

    // ---- main: k = 1..126 as 63 constant-parity pairs, then k=127 ----
    #pragma nounroll
    for (int k = 1; k + 1 < TT; k += 2) {
        STEP(k,     0, 1)      // odd  k: rd=0, wr=1
        STEP(k + 1, 1, 0)      // even k: rd=1, wr=0
    }
    STEP(TT - 1, 0, 1)         // k=127 (odd)

    // ---- k=TT peel: L1 only computes h1(TT-1) -> h1f (fp32); RD=1 ----
    bar_lgkm();
    if (!isL0) {
        half8 g0a = *(const half8*)&h0s[1][lr][q * 8];
        half8 g0b = *(const half8*)&h0s[1][lr][32 + q * 8];
        half8 h1a = *(const half8*)&h1s[1][lr][q * 8];
        half8 h1b = *(const half8*)&h1s[1][lr][32 + q * 8];
        floatx4 a[4];
        #pragma unroll
        for (int g = 0; g < 4; ++g) {
            floatx4 acc = __builtin_amdgcn_mfma_f32_16x16x32_f16(g0a, bi1[g][0], zeroq, 0, 0, 0);
            acc         = __builtin_amdgcn_mfma_f32_16x16x32_f16(g0b, bi1[g][1], acc,   0, 0, 0);
            acc         = __builtin_amdgcn_mfma_f32_16x16x32_f16(h1a, bh1[g][0], acc,   0, 0, 0);
            a[g]        = __builtin_amdgcn_mfma_f32_16x16x32_f16(h1b, bh1[g][1], acc,   0, 0, 0);
        }
        float hnew[4];
        lstm_cell4(a, cr, hnew, nbi, nbf, bg2, nbo);
        #pragma unroll
        for (int r = 0; r < 4; ++r)
            h1f[q * 4 + r][w4 * 16 + lr] = hnew[r];
    }
    __syncthreads();

    // ---- classifier (fp32): hidden = relu(hT Wc1^T + bc1); out = hidden Wc2^T + bc2
    if (tid < 256) {
        int m = tid >> 4;
        int u = (tid & 15) * 2;
        float aa = bc1[u], bb = bc1[u + 1];
        const float* w0 = Wc1 + u * 64;
        const float* w1 = Wc1 + (u + 1) * 64;
        #pragma unroll 8
        for (int kk = 0; kk < 64; ++kk) {
            float hv = h1f[m][kk];
            aa += hv * w0[kk];
            bb += hv * w1[kk];
        }
        hid[m][u]     = fmaxf(aa, 0.f);
        hid[m][u + 1] = fmaxf(bb, 0.f);
    }
    __syncthreads();
    if (tid < 16) {
        float o = bc2[0];
        #pragma unroll
        for (int u = 0; u < 32; ++u) o += hid[tid][u] * Wc2[u];
        out[b0 + tid] = o;
    }
}

extern "C" void kernel_launch(void* const* d_in, const int* in_sizes, int n_in,
                              void* d_out, int out_size, void* d_ws, size_t ws_size,
                              hipStream_t stream) {
    (void)in_sizes; (void)n_in; (void)d_ws; (void)ws_size; (void)out_size;
    const float* x    = (const float*)d_in[0];
    const float* Wih0 = (const float*)d_in[1];
    const float* Whh0 = (const float*)d_in[2];
    const float* bih0 = (const float*)d_in[3];
    const float* bhh0 = (const float*)d_in[4];
    const float* Wih1 = (const float*)d_in[5];
    const float* Whh1 = (const float*)d_in[6];
    const float* bih1 = (const float*)d_in[7];
    const float* bhh1 = (const float*)d_in[8];
    const float* Wc1  = (const float*)d_in[9];
    const float* bc1  = (const float*)d_in[10];
    const float* Wc2  = (const float*)d_in[11];
    const float* bc2  = (const float*)d_in[12];
    lstm_fused<<<dim3(256), dim3(512), 0, stream>>>(
        x, Wih0, Whh0, bih0, bhh0, Wih1, Whh1, bih1, bhh1, Wc1, bc1, Wc2, bc2,
        (float*)d_out);
}

// Round 10
// 203.609 us; speedup vs baseline: 25.7257x; 1.0022x over previous
//
#include <hip/hip_runtime.h>

// LSTMClassifier: B=4096, T=128, I=32, H=64, 2-layer LSTM + MLP head.
// Round 13: R7 (proven best, 120.3us) + T5 s_setprio around MFMA clusters.
//   History: R4 reg-x, R5 counters, R6 slot-split, R8 cross-block ring,
//   R9 fused-wave, R10 addr+barrier diet, R11/R12 tr-read repack -- all
//   null or worse. R7's topology (8 waves, 1 barrier/step, LDS x-staging,
//   dbuf f16 h-state) is the measured optimum. Each SIMD hosts one L0 wave
//   (12 MFMA) + one L1 wave (16 MFMA) = role-split (T5's prerequisite per
//   m218b); setprio(1) around the MFMA chains lets the MFMA-issuing wave
//   win arbitration while the partner wave's eltwise fills VALU gaps.
//   Zero correctness delta. If this is null, the structure is at its
//   serial-recurrence floor (~900ns/step x 128 steps; HBM 3.5%, MFMA 20%).
// Eltwise: R6/R7-validated 24-trans fused cell (absmax 2.44e-4).
// f16 MFMA operands, fp32 accumulate/state. 256 blocks x 512 threads.

#define TT 128
#define II 32

typedef _Float16 half8 __attribute__((ext_vector_type(8)));
typedef float floatx4 __attribute__((ext_vector_type(4)));

#define LOG2E 1.4426950408889634f

__device__ __forceinline__ half8 cvt_frag(float4 a, float4 b) {
    half8 h;
    h[0] = (_Float16)a.x; h[1] = (_Float16)a.y; h[2] = (_Float16)a.z; h[3] = (_Float16)a.w;
    h[4] = (_Float16)b.x; h[5] = (_Float16)b.y; h[6] = (_Float16)b.z; h[7] = (_Float16)b.w;
    return h;
}

// Load 8 consecutive fp32 of row n (K-major) as an f16 MFMA B-fragment.
__device__ __forceinline__ half8 load_w_frag(const float* __restrict__ W, int n, int K, int k0) {
    const float* p = W + (size_t)n * K + k0;
    return cvt_frag(*(const float4*)p, *(const float4*)(p + 4));
}

// LSTM cell eltwise, biases pre-folded (validated R6/R7: absmax 2.44e-4):
//   c = (c_prev*ds + (u-1)*df) * rcp(df*ds); h = (uc-1)*rcp((1+vo)(uc+1));
//   reciprocals paired across r. 24 trans per call.
__device__ __forceinline__ void lstm_cell4(const floatx4* a, float* cr, float* hnew,
                                           float nbi, float nbf, float bg2, float nbo) {
    const float nL  = -LOG2E;
    const float p2L = 2.0f * LOG2E;
    const float C43 = 30.0f * LOG2E;   // |15 * 2L| clamp bound (post-scale)
    float m[4], numc[4];
    #pragma unroll
    for (int r = 0; r < 4; ++r) {
        float vf = __builtin_amdgcn_exp2f(fmaf(a[1][r], nL, nbf));
        float tg = __builtin_amdgcn_fmed3f(fmaf(a[2][r], p2L, bg2), -C43, C43);
        float u  = __builtin_amdgcn_exp2f(tg);
        float vi = __builtin_amdgcn_exp2f(fmaf(a[0][r], nL, nbi));
        float du = u + 1.0f;
        float ds = fmaf(vi, du, du);          // (1+vi)(u+1)
        float df = 1.0f + vf;
        m[r]    = df * ds;
        numc[r] = fmaf(cr[r], ds, (u - 1.0f) * df);
    }
    float r01 = __builtin_amdgcn_rcpf(m[0] * m[1]);
    float r23 = __builtin_amdgcn_rcpf(m[2] * m[3]);
    float c[4];
    c[0] = numc[0] * (r01 * m[1]);
    c[1] = numc[1] * (r01 * m[0]);
    c[2] = numc[2] * (r23 * m[3]);
    c[3] = numc[3] * (r23 * m[2]);
    float dh[4], un[4];
    #pragma unroll
    for (int r = 0; r < 4; ++r) {
        cr[r] = c[r];
        float vo = __builtin_amdgcn_exp2f(fmaf(a[3][r], nL, nbo));
        float tc = __builtin_amdgcn_fmed3f(c[r] * p2L, -C43, C43);
        float uc = __builtin_amdgcn_exp2f(tc);
        float du2 = uc + 1.0f;
        dh[r] = fmaf(vo, du2, du2);           // (1+vo)(uc+1)
        un[r] = uc - 1.0f;
    }
    float s01 = __builtin_amdgcn_rcpf(dh[0] * dh[1]);
    float s23 = __builtin_amdgcn_rcpf(dh[2] * dh[3]);
    hnew[0] = un[0] * (s01 * dh[1]);
    hnew[1] = un[1] * (s01 * dh[0]);
    hnew[2] = un[2] * (s23 * dh[3]);
    hnew[3] = un[3] * (s23 * dh[2]);
}

__global__ __launch_bounds__(512, 2) void lstm_fused(
    const float* __restrict__ x,
    const float* __restrict__ Wih0, const float* __restrict__ Whh0,
    const float* __restrict__ bih0, const float* __restrict__ bhh0,
    const float* __restrict__ Wih1, const float* __restrict__ Whh1,
    const float* __restrict__ bih1, const float* __restrict__ bhh1,
    const float* __restrict__ Wc1, const float* __restrict__ bc1,
    const float* __restrict__ Wc2, const float* __restrict__ bc2,
    float* __restrict__ out)
{
    // 72-f16 row stride (144B): b128 reads at free 2-way bank alias (m136).
    __shared__ __align__(16) _Float16 xs[2][16][40];
    __shared__ __align__(16) _Float16 h0s[2][16][72];
    __shared__ __align__(16) _Float16 h1s[2][16][72];
    __shared__ __align__(16) float h1f[16][68];   // final-step h1 (fp32)
    __shared__ float hid[16][32];

    const int tid  = threadIdx.x;
    const int wid  = tid >> 6;        // wave 0..7
    const int w4   = wid & 3;         // channel-group within the layer
    const bool isL0 = (wid < 4);
    const int lane = tid & 63;
    const int q  = lane >> 4;         // quad 0..3
    const int lr = lane & 15;
    const int b0 = blockIdx.x * 16;

    const float nL  = -LOG2E;
    const float p2L = 2.0f * LOG2E;

    // ---- persistent weight fragments (registers, whole kernel) ----
    // Wave group w4 owns gate-column tiles n = (w4 + 4g)*16: all four gates
    // for channels [16*w4, 16*w4+16) are lane-local at eltwise.
    half8 bx0[4], bh0[4][2];          // layer-0 waves
    half8 bi1[4][2], bh1[4][2];       // layer-1 waves
    float bias[4];
    if (isL0) {
        #pragma unroll
        for (int g = 0; g < 4; ++g) {
            int n = (w4 + 4 * g) * 16 + lr;
            bx0[g]    = load_w_frag(Wih0, n, 32, q * 8);
            bh0[g][0] = load_w_frag(Whh0, n, 64, q * 8);
            bh0[g][1] = load_w_frag(Whh0, n, 64, 32 + q * 8);
            bias[g]   = bih0[n] + bhh0[n];
        }
    } else {
        #pragma unroll
        for (int g = 0; g < 4; ++g) {
            int n = (w4 + 4 * g) * 16 + lr;
            bi1[g][0] = load_w_frag(Wih1, n, 64, q * 8);
            bi1[g][1] = load_w_frag(Wih1, n, 64, 32 + q * 8);
            bh1[g][0] = load_w_frag(Whh1, n, 64, q * 8);
            bh1[g][1] = load_w_frag(Whh1, n, 64, 32 + q * 8);
            bias[g]   = bih1[n] + bhh1[n];
        }
    }
    const float nbi = nL * bias[0], nbf = nL * bias[1];
    const float bg2 = p2L * bias[2], nbo = nL * bias[3];
    const floatx4 zeroq = {0.f, 0.f, 0.f, 0.f};

    // zero-init both h-state buffers (h0(-1) = h1(-1) = 0)
    for (int i = tid; i < 2 * 16 * 72; i += 512) {
        ((_Float16*)h0s)[i] = (_Float16)0.0f;
        ((_Float16*)h1s)[i] = (_Float16)0.0f;
    }

    // x staging (layer-0 waves only): thread -> (row xm, 2 consecutive floats)
    const int xm = (tid >> 4) & 15;
    const int xf = (tid & 15) * 2;
    const float* xrow = x + ((size_t)(b0 + xm) * TT) * II + xf;
    float2 xbuf = {0.f, 0.f};
    if (isL0) {
        float2 x0 = *(const float2*)(xrow);            // x(0) -> xs[0]
        xs[0][xm][xf]     = (_Float16)x0.x;
        xs[0][xm][xf + 1] = (_Float16)x0.y;
        if (TT > 1) xbuf = *(const float2*)(xrow + 1 * II);  // x(1) in regs
    }

    float cr[4] = {0.f, 0.f, 0.f, 0.f};   // c state for this wave's layer

    // Iteration k: waves 0-3 compute h0(k) (k < TT); waves 4-7 compute h1(k-1)
    // (k >= 1). h*(k) is written to buf[k&1]; iter k reads h*(k-1) from
    // buf[(k+1)&1]. x(k) lives in xs[k&1], staged during iter k-1.
    // Single barrier per iter (R7-identical schedule).
    for (int k = 0; k <= TT; ++k) {
        __syncthreads();

        const int rd = (k + 1) & 1;
        const int wr = k & 1;
        const bool doL0 = isL0 && (k < TT);
        const bool doL1 = (!isL0) && (k >= 1);
        floatx4 a[4];
        float hnew[4];
        float2 xnew = xbuf;

        if (doL0) {
            // gates(raw) = x(k) Wih0^T + h0(k-1) Whh0^T  (bias folded in cell)
            half8 xfrag = *(const half8*)&xs[wr][lr][q * 8];      // x(k) in xs[k&1]
            half8 h0a   = *(const half8*)&h0s[rd][lr][q * 8];
            half8 h0b   = *(const half8*)&h0s[rd][lr][32 + q * 8];
            if (k + 2 < TT) xnew = *(const float2*)(xrow + (size_t)(k + 2) * II);
            __builtin_amdgcn_s_setprio(1);           // T5: favor MFMA chain
            #pragma unroll
            for (int g = 0; g < 4; ++g) {
                floatx4 acc = __builtin_amdgcn_mfma_f32_16x16x32_f16(xfrag, bx0[g],    zeroq, 0, 0, 0);
                acc         = __builtin_amdgcn_mfma_f32_16x16x32_f16(h0a,   bh0[g][0], acc,   0, 0, 0);
                a[g]        = __builtin_amdgcn_mfma_f32_16x16x32_f16(h0b,   bh0[g][1], acc,   0, 0, 0);
            }
            __builtin_amdgcn_s_setprio(0);
            lstm_cell4(a, cr, hnew, nbi, nbf, bg2, nbo);
        }
        if (doL1) {
            // gates(raw) = h0(k-1) Wih1^T + h1(k-2) Whh1^T
            half8 g0a = *(const half8*)&h0s[rd][lr][q * 8];
            half8 g0b = *(const half8*)&h0s[rd][lr][32 + q * 8];
            half8 h1a = *(const half8*)&h1s[rd][lr][q * 8];
            half8 h1b = *(const half8*)&h1s[rd][lr][32 + q * 8];
            __builtin_amdgcn_s_setprio(1);           // T5: favor MFMA chain
            #pragma unroll
            for (int g = 0; g < 4; ++g) {
                floatx4 acc = __builtin_amdgcn_mfma_f32_16x16x32_f16(g0a, bi1[g][0], zeroq, 0, 0, 0);
                acc         = __builtin_amdgcn_mfma_f32_16x16x32_f16(g0b, bi1[g][1], acc,   0, 0, 0);
                acc         = __builtin_amdgcn_mfma_f32_16x16x32_f16(h1a, bh1[g][0], acc,   0, 0, 0);
                a[g]        = __builtin_amdgcn_mfma_f32_16x16x32_f16(h1b, bh1[g][1], acc,   0, 0, 0);
            }
            __builtin_amdgcn_s_setprio(0);
            lstm_cell4(a, cr, hnew, nbi, nbf, bg2, nbo);
        }

        // writes go to buf[wr]; readers of buf[wr] are past the next barrier
        if (doL0) {
            #pragma unroll
            for (int r = 0; r < 4; ++r)
                h0s[wr][q * 4 + r][w4 * 16 + lr] = (_Float16)hnew[r];
            if (k + 1 < TT) {                       // stage x(k+1) -> xs[(k+1)&1]
                xs[rd][xm][xf]     = (_Float16)xbuf.x;
                xs[rd][xm][xf + 1] = (_Float16)xbuf.y;
            }
            xbuf = xnew;
        }
        if (doL1) {
            if (k == TT) {
                #pragma unroll
                for (int r = 0; r < 4; ++r)
                    h1f[q * 4 + r][w4 * 16 + lr] = hnew[r];
            } else {
                #pragma unroll
                for (int r = 0; r < 4; ++r)
                    h1s[wr][q * 4 + r][w4 * 16 + lr] = (_Float16)hnew[r];
            }
        }
    }
    __syncthreads();

    // ---- classifier (fp32): hidden = relu(hT Wc1^T + bc1); out = hidden Wc2^T + bc2
    if (tid < 256) {
        int m = tid >> 4;
        int u = (tid & 15) * 2;
        float aa = bc1[u], bb = bc1[u + 1];
        const float* w0 = Wc1 + u * 64;
        const float* w1 = Wc1 + (u + 1) * 64;
        #pragma unroll 8
        for (int kk = 0; kk < 64; ++kk) {
            float hv = h1f[m][kk];
            aa += hv * w0[kk];
            bb += hv * w1[kk];
        }
        hid[m][u]     = fmaxf(aa, 0.f);
        hid[m][u + 1] = fmaxf(bb, 0.f);
    }
    __syncthreads();
    if (tid < 16) {
        float o = bc2[0];
        #pragma unroll
        for (int u = 0; u < 32; ++u) o += hid[tid][u] * Wc2[u];
        out[b0 + tid] = o;
    }
}

extern "C" void kernel_launch(void* const* d_in, const int* in_sizes, int n_in,
                              void* d_out, int out_size, void* d_ws, size_t ws_size,
                              hipStream_t stream) {
    (void)in_sizes; (void)n_in; (void)d_ws; (void)ws_size; (void)out_size;
    const float* x    = (const float*)d_in[0];
    const float* Wih0 = (const float*)d_in[1];
    const float* Whh0 = (const float*)d_in[2];
    const float* bih0 = (const float*)d_in[3];
    const float* bhh0 = (const float*)d_in[4];
    const float* Wih1 = (const float*)d_in[5];
    const float* Whh1 = (const float*)d_in[6];
    const float* bih1 = (const float*)d_in[7];
    const float* bhh1 = (const float*)d_in[8];
    const float* Wc1  = (const float*)d_in[9];
    const float* bc1  = (const float*)d_in[10];
    const float* Wc2  = (const float*)d_in[11];
    const float* bc2  = (const float*)d_in[12];
    lstm_fused<<<dim3(256), dim3(512), 0, stream>>>(
        x, Wih0, Whh0, bih0, bhh0, Wih1, Whh1, bih1, bhh1, Wc1, bc1, Wc2, bc2,
        (float*)d_out);
}